// Round 6
// baseline (2409.472 us; speedup 1.0000x reference)
//
#include <hip/hip_runtime.h>

#define HD 128
#define N_TX 200000
#define N_CARD 80000
#define N_EMAIL 60000
#define NE 250000

// ---------------------------------------------------------------------------
// Generic fused GEMM: out = [relu]( A[M,K] @ W[K,128] (+bias) ).
// Block: 256 threads, 128-row tile. W staged fully in LDS (64 KB).
// Thread t: q = t&3 owns interleaved col chunks c = 16*i + 4*q + j (i<8,j<4)
// (q-dependent bank offsets -> conflict-free broadcast reads), rr = t>>2 owns
// rows {tile+rr, tile+rr+64}. 64 fp32 accumulators per thread.
// In-place (out == A) is safe: each output row depends only on the same input
// row, and only the 4 same-wave threads that read a row ever write it (all
// their reads precede their writes).
// ---------------------------------------------------------------------------
__global__ __launch_bounds__(256) void gemm_k(
    const float* __restrict__ A, const float* __restrict__ W, int M, int K,
    const float* __restrict__ bias, int relu, float* __restrict__ out)
{
    __shared__ float Wlds[128 * 128];   // exactly 64 KiB
    int t = threadIdx.x;
    for (int i = t * 4; i < K * 128; i += 1024) {
        *(float4*)&Wlds[i] = *(const float4*)&W[i];
    }
    __syncthreads();

    int q = t & 3, rr = t >> 2;
    long row0 = (long)blockIdx.x * 128 + rr;
    long row1 = row0 + 64;
    bool v0 = row0 < M, v1 = row1 < M;
    const float* A0 = A + row0 * K;
    const float* A1 = A + row1 * K;

    float acc0[32], acc1[32];
#pragma unroll
    for (int i = 0; i < 32; i++) { acc0[i] = 0.f; acc1[i] = 0.f; }

    for (int k4 = 0; k4 < K; k4 += 4) {
        float4 a0 = v0 ? *(const float4*)(A0 + k4) : make_float4(0.f, 0.f, 0.f, 0.f);
        float4 a1 = v1 ? *(const float4*)(A1 + k4) : make_float4(0.f, 0.f, 0.f, 0.f);
        const float* wbase = &Wlds[k4 * 128 + 4 * q];
#pragma unroll
        for (int kk = 0; kk < 4; kk++) {
            float ak0 = (&a0.x)[kk];
            float ak1 = (&a1.x)[kk];
#pragma unroll
            for (int i = 0; i < 8; i++) {
                float4 w = *(const float4*)(wbase + kk * 128 + 16 * i);
                acc0[i * 4 + 0] += ak0 * w.x; acc0[i * 4 + 1] += ak0 * w.y;
                acc0[i * 4 + 2] += ak0 * w.z; acc0[i * 4 + 3] += ak0 * w.w;
                acc1[i * 4 + 0] += ak1 * w.x; acc1[i * 4 + 1] += ak1 * w.y;
                acc1[i * 4 + 2] += ak1 * w.z; acc1[i * 4 + 3] += ak1 * w.w;
            }
        }
    }

#pragma unroll
    for (int i = 0; i < 8; i++) {
        int col = 16 * i + 4 * q;
        float4 b = bias ? *(const float4*)&bias[col] : make_float4(0.f, 0.f, 0.f, 0.f);
        float h0[4], h1[4];
        h0[0] = acc0[i * 4 + 0] + b.x; h0[1] = acc0[i * 4 + 1] + b.y;
        h0[2] = acc0[i * 4 + 2] + b.z; h0[3] = acc0[i * 4 + 3] + b.w;
        h1[0] = acc1[i * 4 + 0] + b.x; h1[1] = acc1[i * 4 + 1] + b.y;
        h1[2] = acc1[i * 4 + 2] + b.z; h1[3] = acc1[i * 4 + 3] + b.w;
        if (relu) {
#pragma unroll
            for (int j = 0; j < 4; j++) {
                h0[j] = fmaxf(h0[j], 0.f);
                h1[j] = fmaxf(h1[j], 0.f);
            }
        }
        if (v0) *(float4*)&out[row0 * 128 + col] = make_float4(h0[0], h0[1], h0[2], h0[3]);
        if (v1) *(float4*)&out[row1 * 128 + col] = make_float4(h1[0], h1[1], h1[2], h1[3]);
    }
}

// out[w] = sum_c relu(v[w,c]) * Wc[c] + bc   — one 64-lane wave per row
__global__ __launch_bounds__(256) void relu_dot_k(
    const float* __restrict__ v, const float* __restrict__ Wc,
    const float* __restrict__ bcp, float* __restrict__ out, int M)
{
    int w = (blockIdx.x * 256 + threadIdx.x) >> 6;
    if (w >= M) return;
    int lane = threadIdx.x & 63;
    float2 x = *(const float2*)&v[(long)w * 128 + lane * 2];
    float2 c = *(const float2*)&Wc[lane * 2];
    float p = fmaxf(x.x, 0.f) * c.x + fmaxf(x.y, 0.f) * c.y;
#pragma unroll
    for (int off = 32; off > 0; off >>= 1) p += __shfl_xor(p, off);
    if (lane == 0) out[w] = p + bcp[0];
}

// out[is[e]] += vals[ig[e]] * invdeg[is[e]]   (32 threads per edge, float4 lanes)
__global__ __launch_bounds__(256) void scatter_k(
    const float* __restrict__ vals, const int* __restrict__ ig,
    const int* __restrict__ is, const float* __restrict__ invdeg,
    float* __restrict__ out, int E)
{
    int t = blockIdx.x * 256 + threadIdx.x;
    int e = t >> 5;
    if (e >= E) return;
    int lane = t & 31;
    int s = ig[e], d = is[e];
    float sc = invdeg[d];
    float4 v = *(const float4*)&vals[(long)s * 128 + lane * 4];
    float* o = &out[(long)d * 128 + lane * 4];
    atomicAdd(o + 0, v.x * sc);
    atomicAdd(o + 1, v.y * sc);
    atomicAdd(o + 2, v.z * sc);
    atomicAdd(o + 3, v.w * sc);
}

__global__ __launch_bounds__(256) void degree_k(
    const int* __restrict__ tc_src, const int* __restrict__ tc_dst,
    const int* __restrict__ te_src, const int* __restrict__ te_dst,
    int* deg_tx_tc, int* deg_card, int* deg_tx_te, int* deg_email, int E)
{
    int e = blockIdx.x * 256 + threadIdx.x;
    if (e >= E) return;
    atomicAdd(&deg_tx_tc[tc_src[e]], 1);
    atomicAdd(&deg_card[tc_dst[e]], 1);
    atomicAdd(&deg_tx_te[te_src[e]], 1);
    atomicAdd(&deg_email[te_dst[e]], 1);
}

__global__ __launch_bounds__(256) void invdeg_k(const int* __restrict__ deg,
                                                float* __restrict__ inv, int n)
{
    int i = blockIdx.x * 256 + threadIdx.x;
    if (i < n) inv[i] = 1.0f / (float)max(deg[i], 1);
}

// Wsum1 = Wr1[1]+Wr1[3], bsum1 = bl1[1]+bl1[3]; same for layer 2.
__global__ __launch_bounds__(256) void prep_k(
    const float* __restrict__ Wr1, const float* __restrict__ bl1,
    const float* __restrict__ Wr2, const float* __restrict__ bl2,
    float* Wsum1, float* bsum1, float* Wsum2, float* bsum2)
{
    int i = blockIdx.x * 256 + threadIdx.x;
    if (i < 128 * 128) {
        Wsum1[i] = Wr1[1 * 16384 + i] + Wr1[3 * 16384 + i];
        Wsum2[i] = Wr2[1 * 16384 + i] + Wr2[3 * 16384 + i];
    }
    if (i < 128) {
        bsum1[i] = bl1[128 + i] + bl1[3 * 128 + i];
        bsum2[i] = bl2[128 + i] + bl2[3 * 128 + i];
    }
}

extern "C" void kernel_launch(void* const* d_in, const int* in_sizes, int n_in,
                              void* d_out, int out_size, void* d_ws, size_t ws_size,
                              hipStream_t stream)
{
    const float* x_tx  = (const float*)d_in[0];
    const float* W_in  = (const float*)d_in[1];
    const float* b_in  = (const float*)d_in[2];
    const float* Wl1   = (const float*)d_in[3];
    const float* bl1   = (const float*)d_in[4];
    const float* Wr1   = (const float*)d_in[5];
    const float* Wl2   = (const float*)d_in[6];
    const float* bl2   = (const float*)d_in[7];
    const float* Wr2   = (const float*)d_in[8];
    const float* Wc    = (const float*)d_in[9];
    const float* bc    = (const float*)d_in[10];
    const int* tc_src  = (const int*)d_in[11];
    const int* tc_dst  = (const int*)d_in[12];
    const int* te_src  = (const int*)d_in[13];
    const int* te_dst  = (const int*)d_in[14];

    char* ws = (char*)d_ws;
    size_t off = 0;
    auto alloc = [&](size_t n) { float* p = (float*)(ws + off); off += n * 4; return p; };
    // Peak footprint ~178 MB. B1 is reused in sequence:
    //   h_tx -> h1_tx (in place) -> aggZ base (in place GEMM init) -> scatter dst.
    // aggC/aggE: agg -> h1 (in place) -> z (in place).
    float* B1   = alloc(25600000);   // N_TX*128
    float* aggC = alloc(10240000);   // N_CARD*128
    float* aggE = alloc(7680000);    // N_EMAIL*128
    float* inv_tx_tc = alloc(200000);
    float* inv_tx_te = alloc(200000);
    float* inv_card  = alloc(80000);
    float* inv_email = alloc(60000);
    float* Wsum1 = alloc(16384);
    float* Wsum2 = alloc(16384);
    float* bsum1 = alloc(128);
    float* bsum2 = alloc(128);
    int* deg = (int*)(ws + off); off += 540000 * 4;
    int* deg_tx_tc = deg;
    int* deg_tx_te = deg + 200000;
    int* deg_card  = deg + 400000;
    int* deg_email = deg + 480000;

    // --- degrees & inverse degrees (same counts for both layers) ---
    hipMemsetAsync(deg, 0, 540000 * 4, stream);
    degree_k<<<(NE + 255) / 256, 256, 0, stream>>>(tc_src, tc_dst, te_src, te_dst,
        deg_tx_tc, deg_card, deg_tx_te, deg_email, NE);
    invdeg_k<<<(200000 + 255) / 256, 256, 0, stream>>>(deg_tx_tc, inv_tx_tc, 200000);
    invdeg_k<<<(200000 + 255) / 256, 256, 0, stream>>>(deg_tx_te, inv_tx_te, 200000);
    invdeg_k<<<(80000 + 255) / 256, 256, 0, stream>>>(deg_card, inv_card, 80000);
    invdeg_k<<<(60000 + 255) / 256, 256, 0, stream>>>(deg_email, inv_email, 60000);
    prep_k<<<64, 256, 0, stream>>>(Wr1, bl1, Wr2, bl2, Wsum1, bsum1, Wsum2, bsum2);

    // --- input projection: B1 = h_tx = x_tx @ W_in + b_in ---
    gemm_k<<<(N_TX + 127) / 128, 256, 0, stream>>>(x_tx, W_in, N_TX, 64, b_in, 0, B1);

    // --- layer 1: aggregate tx -> card / email (mean folded in at scatter) ---
    hipMemsetAsync(aggC, 0, (size_t)(10240000 + 7680000) * 4, stream);  // aggC+aggE contiguous
    scatter_k<<<(NE * 32 + 255) / 256, 256, 0, stream>>>(B1, tc_src, tc_dst, inv_card, aggC, NE);
    scatter_k<<<(NE * 32 + 255) / 256, 256, 0, stream>>>(B1, te_src, te_dst, inv_email, aggE, NE);

    // h1_card / h1_email IN PLACE over aggC / aggE
    gemm_k<<<(N_CARD + 127) / 128, 256, 0, stream>>>(
        aggC, Wl1 + 0 * 16384, N_CARD, 128, bl1 + 0 * 128, 1, aggC);
    gemm_k<<<(N_EMAIL + 127) / 128, 256, 0, stream>>>(
        aggE, Wl1 + 2 * 16384, N_EMAIL, 128, bl1 + 2 * 128, 1, aggE);
    // h1_tx IN PLACE over B1 (scatters above already consumed h_tx)
    gemm_k<<<(N_TX + 127) / 128, 256, 0, stream>>>(B1, Wsum1, N_TX, 128, bsum1, 1, B1);

    // --- layer 2 (tx only): GEMM before aggregation (linear commutes w/ mean) ---
    gemm_k<<<(N_CARD + 127) / 128, 256, 0, stream>>>(
        aggC, Wl2 + 1 * 16384, N_CARD, 128, nullptr, 0, aggC);   // z_card
    gemm_k<<<(N_EMAIL + 127) / 128, 256, 0, stream>>>(
        aggE, Wl2 + 3 * 16384, N_EMAIL, 128, nullptr, 0, aggE);  // z_email

    // --- B1 = h1_tx@Wsum2 + bsum2 (in place; h1_tx dead after) ---
    gemm_k<<<(N_TX + 127) / 128, 256, 0, stream>>>(B1, Wsum2, N_TX, 128, bsum2, 0, B1);

    // --- scatter z_card/z_email ONTO the GEMM base (no memset needed) ---
    scatter_k<<<(NE * 32 + 255) / 256, 256, 0, stream>>>(aggC, tc_dst, tc_src, inv_tx_tc, B1, NE);
    scatter_k<<<(NE * 32 + 255) / 256, 256, 0, stream>>>(aggE, te_dst, te_src, inv_tx_te, B1, NE);

    // --- final: out = relu(B1) @ Wc + bc ---
    relu_dot_k<<<(N_TX * 64 + 255) / 256, 256, 0, stream>>>(B1, Wc, bc, (float*)d_out, N_TX);
}

// Round 7
// 908.671 us; speedup vs baseline: 2.6516x; 2.6516x over previous
//
#include <hip/hip_runtime.h>

#define HD 128
#define N_TX 200000
#define N_CARD 80000
#define N_EMAIL 60000
#define NE 250000
// concatenated CSR segment offsets (by dst-node key):
//   [0,200k)    tx keyed by tc (vals = card ids)
//   [200k,400k) tx keyed by te (vals = email ids)
//   [400k,480k) card (vals = tx ids)
//   [480k,540k) email (vals = tx ids)
#define SEG_TX_TC 0
#define SEG_TX_TE 200000
#define SEG_CARD  400000
#define SEG_EMAIL 480000
#define NSEG 540000

// ---------------------------------------------------------------------------
// Generic fused GEMM: out = [relu]( A[M,K] @ W[K,128] (+bias) ).
// 256 threads, 128-row tile, W resident in 64 KiB LDS.
// In-place (out == A) safe: each output row depends only on the same input
// row, and only the 4 same-wave threads that read a row ever write it.
// ---------------------------------------------------------------------------
__global__ __launch_bounds__(256) void gemm_k(
    const float* __restrict__ A, const float* __restrict__ W, int M, int K,
    const float* __restrict__ bias, int relu, float* __restrict__ out)
{
    __shared__ float Wlds[128 * 128];
    int t = threadIdx.x;
    for (int i = t * 4; i < K * 128; i += 1024) {
        *(float4*)&Wlds[i] = *(const float4*)&W[i];
    }
    __syncthreads();

    int q = t & 3, rr = t >> 2;
    long row0 = (long)blockIdx.x * 128 + rr;
    long row1 = row0 + 64;
    bool v0 = row0 < M, v1 = row1 < M;
    const float* A0 = A + row0 * K;
    const float* A1 = A + row1 * K;

    float acc0[32], acc1[32];
#pragma unroll
    for (int i = 0; i < 32; i++) { acc0[i] = 0.f; acc1[i] = 0.f; }

    for (int k4 = 0; k4 < K; k4 += 4) {
        float4 a0 = v0 ? *(const float4*)(A0 + k4) : make_float4(0.f, 0.f, 0.f, 0.f);
        float4 a1 = v1 ? *(const float4*)(A1 + k4) : make_float4(0.f, 0.f, 0.f, 0.f);
        const float* wbase = &Wlds[k4 * 128 + 4 * q];
#pragma unroll
        for (int kk = 0; kk < 4; kk++) {
            float ak0 = (&a0.x)[kk];
            float ak1 = (&a1.x)[kk];
#pragma unroll
            for (int i = 0; i < 8; i++) {
                float4 w = *(const float4*)(wbase + kk * 128 + 16 * i);
                acc0[i * 4 + 0] += ak0 * w.x; acc0[i * 4 + 1] += ak0 * w.y;
                acc0[i * 4 + 2] += ak0 * w.z; acc0[i * 4 + 3] += ak0 * w.w;
                acc1[i * 4 + 0] += ak1 * w.x; acc1[i * 4 + 1] += ak1 * w.y;
                acc1[i * 4 + 2] += ak1 * w.z; acc1[i * 4 + 3] += ak1 * w.w;
            }
        }
    }

#pragma unroll
    for (int i = 0; i < 8; i++) {
        int col = 16 * i + 4 * q;
        float4 b = bias ? *(const float4*)&bias[col] : make_float4(0.f, 0.f, 0.f, 0.f);
        float h0[4], h1[4];
        h0[0] = acc0[i * 4 + 0] + b.x; h0[1] = acc0[i * 4 + 1] + b.y;
        h0[2] = acc0[i * 4 + 2] + b.z; h0[3] = acc0[i * 4 + 3] + b.w;
        h1[0] = acc1[i * 4 + 0] + b.x; h1[1] = acc1[i * 4 + 1] + b.y;
        h1[2] = acc1[i * 4 + 2] + b.z; h1[3] = acc1[i * 4 + 3] + b.w;
        if (relu) {
#pragma unroll
            for (int j = 0; j < 4; j++) {
                h0[j] = fmaxf(h0[j], 0.f);
                h1[j] = fmaxf(h1[j], 0.f);
            }
        }
        if (v0) *(float4*)&out[row0 * 128 + col] = make_float4(h0[0], h0[1], h0[2], h0[3]);
        if (v1) *(float4*)&out[row1 * 128 + col] = make_float4(h1[0], h1[1], h1[2], h1[3]);
    }
}

// out[w] = sum_c relu(v[w,c]) * Wc[c] + bc   — one 64-lane wave per row
__global__ __launch_bounds__(256) void relu_dot_k(
    const float* __restrict__ v, const float* __restrict__ Wc,
    const float* __restrict__ bcp, float* __restrict__ out, int M)
{
    int w = (blockIdx.x * 256 + threadIdx.x) >> 6;
    if (w >= M) return;
    int lane = threadIdx.x & 63;
    float2 x = *(const float2*)&v[(long)w * 128 + lane * 2];
    float2 c = *(const float2*)&Wc[lane * 2];
    float p = fmaxf(x.x, 0.f) * c.x + fmaxf(x.y, 0.f) * c.y;
#pragma unroll
    for (int off = 32; off > 0; off >>= 1) p += __shfl_xor(p, off);
    if (lane == 0) out[w] = p + bcp[0];
}

// ---- degree histograms (4 keys at once) ----
__global__ __launch_bounds__(256) void degree_k(
    const int* __restrict__ tc_src, const int* __restrict__ tc_dst,
    const int* __restrict__ te_src, const int* __restrict__ te_dst,
    int* deg, int E)
{
    int e = blockIdx.x * 256 + threadIdx.x;
    if (e >= E) return;
    atomicAdd(&deg[SEG_TX_TC + tc_src[e]], 1);
    atomicAdd(&deg[SEG_TX_TE + te_src[e]], 1);
    atomicAdd(&deg[SEG_CARD  + tc_dst[e]], 1);
    atomicAdd(&deg[SEG_EMAIL + te_dst[e]], 1);
}

// ---- 3-kernel exclusive scan over the 540k concatenated degrees ----
__global__ __launch_bounds__(256) void scan1_k(const int* __restrict__ in,
                                               int* __restrict__ out,
                                               int* __restrict__ bsums, int n)
{
    __shared__ int lds[256];
    int b = blockIdx.x, t = threadIdx.x;
    int base = b * 1024 + t * 4;
    int4 v = make_int4(0, 0, 0, 0);
    if (base + 3 < n) v = *(const int4*)&in[base];
    else {
        if (base + 0 < n) v.x = in[base + 0];
        if (base + 1 < n) v.y = in[base + 1];
        if (base + 2 < n) v.z = in[base + 2];
    }
    int s = v.x + v.y + v.z + v.w;
    lds[t] = s;
    __syncthreads();
    for (int off = 1; off < 256; off <<= 1) {
        int val = (t >= off) ? lds[t - off] : 0;
        __syncthreads();
        lds[t] += val;
        __syncthreads();
    }
    int excl = lds[t] - s;
    if (t == 255) bsums[b] = lds[255];
    int p0 = excl, p1 = p0 + v.x, p2 = p1 + v.y, p3 = p2 + v.z;
    if (base + 0 < n) out[base + 0] = p0;
    if (base + 1 < n) out[base + 1] = p1;
    if (base + 2 < n) out[base + 2] = p2;
    if (base + 3 < n) out[base + 3] = p3;
}

__global__ __launch_bounds__(256) void scan2_k(int* bsums, int nb)
{
    __shared__ int lds[256];
    int t = threadIdx.x;
    int carry = 0;
    for (int start = 0; start < nb; start += 256) {
        int i = start + t;
        int s = (i < nb) ? bsums[i] : 0;
        lds[t] = s;
        __syncthreads();
        for (int off = 1; off < 256; off <<= 1) {
            int v = (t >= off) ? lds[t - off] : 0;
            __syncthreads();
            lds[t] += v;
            __syncthreads();
        }
        if (i < nb) bsums[i] = carry + lds[t] - s;
        carry += lds[255];
        __syncthreads();
    }
}

// add block offsets; also emit cursor copy for the fill pass
__global__ __launch_bounds__(256) void scan3_k(int* __restrict__ rowptr,
                                               int* __restrict__ cursor,
                                               const int* __restrict__ bsums, int n)
{
    int i = blockIdx.x * 256 + threadIdx.x;
    if (i < n) {
        int v = rowptr[i] + bsums[i >> 10];
        rowptr[i] = v;
        cursor[i] = v;
    }
}

// fill all 4 CSR segments' colidx (global positions into concatenated colidx)
__global__ __launch_bounds__(256) void fill_k(
    const int* __restrict__ tc_src, const int* __restrict__ tc_dst,
    const int* __restrict__ te_src, const int* __restrict__ te_dst,
    int* __restrict__ cursor, int* __restrict__ colidx, int E)
{
    int e = blockIdx.x * 256 + threadIdx.x;
    if (e >= E) return;
    int s = tc_src[e], d = tc_dst[e];
    int p = atomicAdd(&cursor[SEG_TX_TC + s], 1); colidx[p] = d;
    p = atomicAdd(&cursor[SEG_CARD + d], 1);      colidx[p] = s;
    s = te_src[e]; d = te_dst[e];
    p = atomicAdd(&cursor[SEG_TX_TE + s], 1);     colidx[p] = d;
    p = atomicAdd(&cursor[SEG_EMAIL + d], 1);     colidx[p] = s;
}

// out[d] = (1/max(deg,1)) * sum_{s in N(d)} vals[s]   — one wave per dst row
__global__ __launch_bounds__(256) void gather_mean_k(
    const float* __restrict__ vals, const int* __restrict__ rowptr,
    const int* __restrict__ deg, const int* __restrict__ colidx,
    float* __restrict__ out, int n)
{
    int w = (blockIdx.x * 256 + threadIdx.x) >> 6;
    if (w >= n) return;
    int lane = threadIdx.x & 63;
    int start = rowptr[w], dg = deg[w];
    float2 acc = make_float2(0.f, 0.f);
    for (int e = start; e < start + dg; ++e) {
        int s = colidx[e];
        float2 v = *(const float2*)&vals[(long)s * 128 + lane * 2];
        acc.x += v.x; acc.y += v.y;
    }
    float sc = 1.f / (float)max(dg, 1);
    *(float2*)&out[(long)w * 128 + lane * 2] = make_float2(acc.x * sc, acc.y * sc);
}

// B[d] += mean_tc(zC) + mean_te(zE)  — fused dual-relation gather, in place
__global__ __launch_bounds__(256) void gather2_k(
    const float* __restrict__ zC, const float* __restrict__ zE,
    const int* __restrict__ rowptr, const int* __restrict__ deg,
    const int* __restrict__ colidx, float* __restrict__ B, int n)
{
    int w = (blockIdx.x * 256 + threadIdx.x) >> 6;
    if (w >= n) return;
    int lane = threadIdx.x & 63;
    float2 acc = *(const float2*)&B[(long)w * 128 + lane * 2];

    int start = rowptr[SEG_TX_TC + w], dg = deg[SEG_TX_TC + w];
    float2 a = make_float2(0.f, 0.f);
    for (int e = start; e < start + dg; ++e) {
        int s = colidx[e];
        float2 v = *(const float2*)&zC[(long)s * 128 + lane * 2];
        a.x += v.x; a.y += v.y;
    }
    float sc = 1.f / (float)max(dg, 1);
    acc.x += a.x * sc; acc.y += a.y * sc;

    start = rowptr[SEG_TX_TE + w]; dg = deg[SEG_TX_TE + w];
    a = make_float2(0.f, 0.f);
    for (int e = start; e < start + dg; ++e) {
        int s = colidx[e];
        float2 v = *(const float2*)&zE[(long)s * 128 + lane * 2];
        a.x += v.x; a.y += v.y;
    }
    sc = 1.f / (float)max(dg, 1);
    acc.x += a.x * sc; acc.y += a.y * sc;

    *(float2*)&B[(long)w * 128 + lane * 2] = acc;
}

// Wsum1 = Wr1[1]+Wr1[3], bsum1 = bl1[1]+bl1[3]; same for layer 2.
__global__ __launch_bounds__(256) void prep_k(
    const float* __restrict__ Wr1, const float* __restrict__ bl1,
    const float* __restrict__ Wr2, const float* __restrict__ bl2,
    float* Wsum1, float* bsum1, float* Wsum2, float* bsum2)
{
    int i = blockIdx.x * 256 + threadIdx.x;
    if (i < 128 * 128) {
        Wsum1[i] = Wr1[1 * 16384 + i] + Wr1[3 * 16384 + i];
        Wsum2[i] = Wr2[1 * 16384 + i] + Wr2[3 * 16384 + i];
    }
    if (i < 128) {
        bsum1[i] = bl1[128 + i] + bl1[3 * 128 + i];
        bsum2[i] = bl2[128 + i] + bl2[3 * 128 + i];
    }
}

extern "C" void kernel_launch(void* const* d_in, const int* in_sizes, int n_in,
                              void* d_out, int out_size, void* d_ws, size_t ws_size,
                              hipStream_t stream)
{
    const float* x_tx  = (const float*)d_in[0];
    const float* W_in  = (const float*)d_in[1];
    const float* b_in  = (const float*)d_in[2];
    const float* Wl1   = (const float*)d_in[3];
    const float* bl1   = (const float*)d_in[4];
    const float* Wr1   = (const float*)d_in[5];
    const float* Wl2   = (const float*)d_in[6];
    const float* bl2   = (const float*)d_in[7];
    const float* Wr2   = (const float*)d_in[8];
    const float* Wc    = (const float*)d_in[9];
    const float* bc    = (const float*)d_in[10];
    const int* tc_src  = (const int*)d_in[11];
    const int* tc_dst  = (const int*)d_in[12];
    const int* te_src  = (const int*)d_in[13];
    const int* te_dst  = (const int*)d_in[14];

    char* ws = (char*)d_ws;
    size_t off = 0;
    auto alloc = [&](size_t n) { float* p = (float*)(ws + off); off += n * 4; return p; };
    // ~185 MB total. B1: h_tx -> h1_tx (in place) -> base (in place) -> +agg (in place).
    // aggC/aggE: agg -> h1 (in place) -> z (in place).
    float* B1   = alloc(25600000);   // N_TX*128
    float* aggC = alloc(10240000);   // N_CARD*128
    float* aggE = alloc(7680000);    // N_EMAIL*128
    float* Wsum1 = alloc(16384);
    float* Wsum2 = alloc(16384);
    float* bsum1 = alloc(128);
    float* bsum2 = alloc(128);
    int* deg    = (int*)(ws + off); off += (size_t)NSEG * 4;
    int* rowptr = (int*)(ws + off); off += (size_t)NSEG * 4;
    int* cursor = (int*)(ws + off); off += (size_t)NSEG * 4;
    int* colidx = (int*)(ws + off); off += (size_t)(4 * NE) * 4;
    int* bsums  = (int*)(ws + off); off += 1024 * 4;

    const int NB = (NSEG + 1023) / 1024;   // 528 scan blocks

    // --- CSR build: degrees -> exclusive scan -> fill ---
    hipMemsetAsync(deg, 0, (size_t)NSEG * 4, stream);
    degree_k<<<(NE + 255) / 256, 256, 0, stream>>>(tc_src, tc_dst, te_src, te_dst, deg, NE);
    scan1_k<<<NB, 256, 0, stream>>>(deg, rowptr, bsums, NSEG);
    scan2_k<<<1, 256, 0, stream>>>(bsums, NB);
    scan3_k<<<(NSEG + 255) / 256, 256, 0, stream>>>(rowptr, cursor, bsums, NSEG);
    fill_k<<<(NE + 255) / 256, 256, 0, stream>>>(tc_src, tc_dst, te_src, te_dst,
                                                 cursor, colidx, NE);
    prep_k<<<64, 256, 0, stream>>>(Wr1, bl1, Wr2, bl2, Wsum1, bsum1, Wsum2, bsum2);

    // --- input projection: B1 = h_tx = x_tx @ W_in + b_in ---
    gemm_k<<<(N_TX + 127) / 128, 256, 0, stream>>>(x_tx, W_in, N_TX, 64, b_in, 0, B1);

    // --- layer 1: mean-gather tx -> card / email (no atomics, no memset) ---
    gather_mean_k<<<(N_CARD * 64 + 255) / 256, 256, 0, stream>>>(
        B1, rowptr + SEG_CARD, deg + SEG_CARD, colidx, aggC, N_CARD);
    gather_mean_k<<<(N_EMAIL * 64 + 255) / 256, 256, 0, stream>>>(
        B1, rowptr + SEG_EMAIL, deg + SEG_EMAIL, colidx, aggE, N_EMAIL);

    // h1_card / h1_email IN PLACE over aggC / aggE
    gemm_k<<<(N_CARD + 127) / 128, 256, 0, stream>>>(
        aggC, Wl1 + 0 * 16384, N_CARD, 128, bl1 + 0 * 128, 1, aggC);
    gemm_k<<<(N_EMAIL + 127) / 128, 256, 0, stream>>>(
        aggE, Wl1 + 2 * 16384, N_EMAIL, 128, bl1 + 2 * 128, 1, aggE);
    // h1_tx IN PLACE over B1 (gathers above already consumed h_tx)
    gemm_k<<<(N_TX + 127) / 128, 256, 0, stream>>>(B1, Wsum1, N_TX, 128, bsum1, 1, B1);

    // --- layer 2 (tx only): GEMM before aggregation (linear commutes w/ mean) ---
    gemm_k<<<(N_CARD + 127) / 128, 256, 0, stream>>>(
        aggC, Wl2 + 1 * 16384, N_CARD, 128, nullptr, 0, aggC);   // z_card
    gemm_k<<<(N_EMAIL + 127) / 128, 256, 0, stream>>>(
        aggE, Wl2 + 3 * 16384, N_EMAIL, 128, nullptr, 0, aggE);  // z_email

    // --- B1 = h1_tx@Wsum2 + bsum2 (in place), then fused dual gather onto it ---
    gemm_k<<<(N_TX + 127) / 128, 256, 0, stream>>>(B1, Wsum2, N_TX, 128, bsum2, 0, B1);
    gather2_k<<<(N_TX * 64 + 255) / 256, 256, 0, stream>>>(
        aggC, aggE, rowptr, deg, colidx, B1, N_TX);

    // --- final: out = relu(B1) @ Wc + bc ---
    relu_dot_k<<<(N_TX * 64 + 255) / 256, 256, 0, stream>>>(B1, Wc, bc, (float*)d_out, N_TX);
}